// Round 2
// baseline (531.688 us; speedup 1.0000x reference)
//
#include <hip/hip_runtime.h>

// Seq2Seq LSTM (enc 512 + dec 256 steps), H=50, B=2048, in/out dim 1.
//
// Round-14 (resubmit; r14 bench was an infra failure, never ran):
// r13 skeleton (MB=4, row-duplication, 1 barrier/step) with the
// step critical path shortened:
//  (a) each gate's 6-deep dependent MFMA chain is split into two depth-3
//      chains (kt0 / kt1 products) + one scalar add -- only acc[0] is ever
//      consumed, so the combine is 1 VALU op, and the chain-latency term
//      halves (6*Lmfma -> 3*Lmfma + add).
//  (b) decoder y-feedback moved off the MFMA path: C-init = bias, the
//      x-part (wx*xc) is added post-MFMA, so the pb round-trip (shfl x4 +
//      LDS read after barrier) overlaps ds_read(h)+MFMA of the next step.
//
// Fragments (verified r10-r12, absmax 4.9e-4):
//   A[m=lane&15][k=kg*8+j]  B[n=nl][k=kt*32+kg*8+j]  D row=4*kg+r, col=nl.
// A-row m carries batch m>>2 (duplication) so every lane's gates live in
// REG 0 of each accumulator. L2E folded into weights/bias (gate g doubled
// -> tanh via sigm).

#define HID 50
#define SEQ 512
#define TGT 256
#define MB  4
#define L2E 1.44269504088896341f

typedef __attribute__((ext_vector_type(8))) short short8;
typedef __attribute__((ext_vector_type(4))) float f32x4;

__device__ __forceinline__ unsigned short f2bf(float f) {   // RNE fp32->bf16
    unsigned u = __float_as_uint(f);
    return (unsigned short)((u + 0x7fffu + ((u >> 16) & 1u)) >> 16);
}
__device__ __forceinline__ float bf2f(unsigned short b) {
    return __uint_as_float(((unsigned)b) << 16);
}
__device__ __forceinline__ float sigm2(float a) {   // a pre-scaled by L2E
    return __builtin_amdgcn_rcpf(1.0f + __builtin_amdgcn_exp2f(-a));
}
__device__ __forceinline__ float tanhc(float c) {   // c in linear domain
    return fmaf(2.0f,
        __builtin_amdgcn_rcpf(1.0f + __builtin_amdgcn_exp2f(-2.0f * L2E * c)),
        -1.0f);
}

#define MFMA(A, B, C) __builtin_amdgcn_mfma_f32_16x16x32_bf16((A), (B), (C), 0, 0, 0)

// h layout: block (split s, k-tile kt, k-octet qg) = 4 batches x 8 k shorts.
#define HB(s, kt, qg) ((((s) * 2 + (kt)) * 4 + (qg)) * 32)
#define HFSZ (2 * 2 * 4 * 32)   // 512 shorts

// One step. POSTX=0: C-init = fmaf(wx, XK, bb) (x known early, encoder).
// POSTX=1: C-init = bb; gate gets + wx*xc AFTER the MFMA chains so the
// decoder y-feedback overlaps the gemv. Updates cc; defines hv; writes h.
#define GCOREX(XK, POSTX, HIN, HOUT)                                   \
    float hv;                                                          \
    {                                                                  \
        const short* hin_ = (HIN);                                     \
        short8 a00 = *(const short8*)(hin_ + HB(0, 0, kg) + bsel * 8); \
        short8 a10 = *(const short8*)(hin_ + HB(0, 1, kg) + bsel * 8); \
        short8 a01 = *(const short8*)(hin_ + HB(1, 0, kg) + bsel * 8); \
        short8 a11 = *(const short8*)(hin_ + HB(1, 1, kg) + bsel * 8); \
        float i0, i1, i2, i3;                                          \
        if (POSTX) {                                                   \
            i0 = bb[0]; i1 = bb[1]; i2 = bb[2]; i3 = bb[3];            \
        } else {                                                       \
            i0 = fmaf(wx[0], (XK), bb[0]);                             \
            i1 = fmaf(wx[1], (XK), bb[1]);                             \
            i2 = fmaf(wx[2], (XK), bb[2]);                             \
            i3 = fmaf(wx[3], (XK), bb[3]);                             \
        }                                                              \
        f32x4 cA0 = {i0, i0, i0, i0};                                  \
        f32x4 cA1 = {i1, i1, i1, i1};                                  \
        f32x4 cA2 = {i2, i2, i2, i2};                                  \
        f32x4 cA3 = {i3, i3, i3, i3};                                  \
        f32x4 cB0 = {0.0f, 0.0f, 0.0f, 0.0f};                          \
        f32x4 cB1 = cB0, cB2 = cB0, cB3 = cB0;                         \
        cA0 = MFMA(a00, Bf[0][0][0], cA0);                             \
        cB0 = MFMA(a10, Bf[0][1][0], cB0);                             \
        cA1 = MFMA(a00, Bf[1][0][0], cA1);                             \
        cB1 = MFMA(a10, Bf[1][1][0], cB1);                             \
        cA2 = MFMA(a00, Bf[2][0][0], cA2);                             \
        cB2 = MFMA(a10, Bf[2][1][0], cB2);                             \
        cA3 = MFMA(a00, Bf[3][0][0], cA3);                             \
        cB3 = MFMA(a10, Bf[3][1][0], cB3);                             \
        cA0 = MFMA(a00, Bf[0][0][1], cA0);                             \
        cB0 = MFMA(a10, Bf[0][1][1], cB0);                             \
        cA1 = MFMA(a00, Bf[1][0][1], cA1);                             \
        cB1 = MFMA(a10, Bf[1][1][1], cB1);                             \
        cA2 = MFMA(a00, Bf[2][0][1], cA2);                             \
        cB2 = MFMA(a10, Bf[2][1][1], cB2);                             \
        cA3 = MFMA(a00, Bf[3][0][1], cA3);                             \
        cB3 = MFMA(a10, Bf[3][1][1], cB3);                             \
        cA0 = MFMA(a01, Bf[0][0][0], cA0);                             \
        cB0 = MFMA(a11, Bf[0][1][0], cB0);                             \
        cA1 = MFMA(a01, Bf[1][0][0], cA1);                             \
        cB1 = MFMA(a11, Bf[1][1][0], cB1);                             \
        cA2 = MFMA(a01, Bf[2][0][0], cA2);                             \
        cB2 = MFMA(a11, Bf[2][1][0], cB2);                             \
        cA3 = MFMA(a01, Bf[3][0][0], cA3);                             \
        cB3 = MFMA(a11, Bf[3][1][0], cB3);                             \
        float s0 = cA0[0] + cB0[0];                                    \
        float s1 = cA1[0] + cB1[0];                                    \
        float s2 = cA2[0] + cB2[0];                                    \
        float s3 = cA3[0] + cB3[0];                                    \
        if (POSTX) {                                                   \
            s0 = fmaf(wx[0], xc, s0);                                  \
            s1 = fmaf(wx[1], xc, s1);                                  \
            s2 = fmaf(wx[2], xc, s2);                                  \
            s3 = fmaf(wx[3], xc, s3);                                  \
        }                                                              \
        float vi = sigm2(s0);                                          \
        float vf = sigm2(s1);                                          \
        float vg = fmaf(2.0f, sigm2(s2), -1.0f);                       \
        float vo = sigm2(s3);                                          \
        cc = fmaf(vf, cc, vi * vg);                                    \
        hv = vo * tanhc(cc);                                           \
        unsigned short q0 = f2bf(hv);                                  \
        unsigned short q1 = f2bf(hv - bf2f(q0));                       \
        short* ho_ = (HOUT);                                           \
        ho_[wr0] = (short)q0;                                          \
        ho_[wr1] = (short)q1;                                          \
    }

// Decoder step: GCOREX(bias-init) + 16-lane fc butterfly -> pb; barrier;
// y rebuild in every lane; out write; feedback (consumed post-MFMA next step).
#define DSTEP(T, HIN, HOUT, PB)                                        \
    {                                                                  \
        GCOREX(0.0f, 1, HIN, HOUT)                                     \
        float p = fcw * hv;                                            \
        p += __shfl_xor(p, 1, 64);                                     \
        p += __shfl_xor(p, 2, 64);                                     \
        p += __shfl_xor(p, 4, 64);                                     \
        p += __shfl_xor(p, 8, 64);                                     \
        if (nl == 0) (PB)[kg * 4 + w] = p;                             \
        __syncthreads();                                               \
        f32x4 s_ = *(const f32x4*)&(PB)[kg * 4];                       \
        float y = s_[0] + s_[1] + s_[2] + s_[3] + fb;                  \
        if (w == 0 && nl == 0) out[(size_t)(b0 + kg) * TGT + (T)] = y; \
        xc = y;                                                        \
    }

extern "C" __global__ void __launch_bounds__(256, 2)
seq2seq_kernel(const float* __restrict__ src,
               const float* __restrict__ eWih, const float* __restrict__ eWhh,
               const float* __restrict__ eBih, const float* __restrict__ eBhh,
               const float* __restrict__ dWih, const float* __restrict__ dWhh,
               const float* __restrict__ dBih, const float* __restrict__ dBhh,
               const float* __restrict__ fcW, const float* __restrict__ fcB,
               float* __restrict__ out) {
    const int tid  = threadIdx.x;        // 0..255
    const int lane = tid & 63;
    const int w    = tid >> 6;           // wave 0..3 = unit tile
    const int nl   = lane & 15;          // n-col within tile
    const int kg   = lane >> 4;          // k-octet; ALSO this lane's batch
    const int bsel = nl >> 2;            // A-row m -> batch m>>2
    const int un   = 16 * w + nl;        // this lane's unit
    const int b0   = blockIdx.x * MB;
    const int ukt  = un >> 5, uqg = (un >> 3) & 3, uj = un & 7;
    const int wr0  = HB(0, ukt, uqg) + kg * 8 + uj;   // h split-0 write
    const int wr1  = HB(1, ukt, uqg) + kg * 8 + uj;   // h split-1 write

    __shared__ __align__(16) short hfA[HFSZ], hfB[HFSZ];  // h splits, dbuf
    __shared__ __align__(16) float srcT[SEQ * MB];        // [t][4 batches]
    __shared__ __align__(16) float pbA[16], pbB[16];      // fc partials [b][w]

    for (int i = tid; i < HFSZ; i += 256) { hfA[i] = 0; hfB[i] = 0; }
    for (int i = tid; i < SEQ * MB; i += 256) {
        int e = i >> 9, t = i & 511;                      // coalesced in t
        srcT[t * MB + e] = src[(size_t)(b0 + e) * SEQ + t];
    }

    short8 Bf[4][2][2];                  // [gate][kt][split] (AGPR-friendly)
    float bb[4], wx[4];
    float cc = 0.0f;                     // cell (batch kg, unit un)
    float xc = 0.0f;                     // decoder feedback (dead in encoder)

    auto loadW = [&](const float* Wih, const float* Whh,
                     const float* Bih, const float* Bhh) {
#pragma unroll
        for (int g = 0; g < 4; ++g) {
            const float sc = (g == 2) ? 2.0f * L2E : L2E;  // tanh fold
            const bool nv  = (un < HID);
            const int row  = g * HID + (nv ? un : 0);      // PyTorch g*50+u
            bb[g] = nv ? (Bih[row] + Bhh[row]) * sc : 0.0f;
            wx[g] = nv ? Wih[row] * sc : 0.0f;
#pragma unroll
            for (int kt = 0; kt < 2; ++kt) {
                short8 s0, s1;
#pragma unroll
                for (int j = 0; j < 8; ++j) {
                    int kk = kt * 32 + kg * 8 + j;
                    float wv = (nv && kk < HID)
                             ? Whh[(size_t)row * HID + kk] * sc : 0.0f;
                    unsigned short h0 = f2bf(wv);
                    unsigned short h1 = f2bf(wv - bf2f(h0));
                    s0[j] = (short)h0; s1[j] = (short)h1;
                }
                Bf[g][kt][0] = s0; Bf[g][kt][1] = s1;
            }
        }
    };

    // ---------------- encoder: 512 steps (x2 unroll) ----------------
    loadW(eWih, eWhh, eBih, eBhh);
    __syncthreads();                     // hf zero + srcT staged
    for (int t = 0; t < SEQ; t += 2) {
        { GCOREX(srcT[t * MB + kg], 0, hfA, hfB) }
        __syncthreads();
        { GCOREX(srcT[(t + 1) * MB + kg], 0, hfB, hfA) }
        __syncthreads();
    }
    // state in hfA

    // ---------------- decoder: 256 steps (x2 unroll) ----------------
    loadW(dWih, dWhh, dBih, dBhh);
    const float fcw = (un < HID) ? fcW[un] : 0.0f;
    const float fb  = fcB[0];
    for (int t = 0; t < TGT; t += 2) {
        DSTEP(t,     hfA, hfB, pbA)
        DSTEP(t + 1, hfB, hfA, pbB)
    }
}

extern "C" void kernel_launch(void* const* d_in, const int* in_sizes, int n_in,
                              void* d_out, int out_size, void* d_ws, size_t ws_size,
                              hipStream_t stream) {
    const float* src  = (const float*)d_in[0];
    const float* eWih = (const float*)d_in[1];
    const float* eWhh = (const float*)d_in[2];
    const float* eBih = (const float*)d_in[3];
    const float* eBhh = (const float*)d_in[4];
    const float* dWih = (const float*)d_in[5];
    const float* dWhh = (const float*)d_in[6];
    const float* dBih = (const float*)d_in[7];
    const float* dBhh = (const float*)d_in[8];
    const float* fcW  = (const float*)d_in[9];
    const float* fcB  = (const float*)d_in[10];
    float* out = (float*)d_out;

    const int B = in_sizes[0] / SEQ;     // 2048
    seq2seq_kernel<<<B / MB, 256, 0, stream>>>(src, eWih, eWhh, eBih, eBhh,
                                               dWih, dWhh, dBih, dBhh,
                                               fcW, fcB, out);
}